// Round 5
// baseline (256.687 us; speedup 1.0000x reference)
//
#include <hip/hip_runtime.h>
#include <stdint.h>

typedef unsigned short u16;
typedef __attribute__((ext_vector_type(8))) short bf16x8;
typedef __attribute__((ext_vector_type(4))) float f32x4;
typedef __attribute__((ext_vector_type(4))) unsigned short us4;

#define MFMA_BF16(a, b, c) __builtin_amdgcn_mfma_f32_16x16x32_bf16((a), (b), (c), 0, 0, 0)

__device__ __forceinline__ u16 f2bf(float f) {
  uint32_t u = __builtin_bit_cast(uint32_t, f);
  u += 0x7fffu + ((u >> 16) & 1u);
  return (u16)(u >> 16);
}

__device__ __forceinline__ void async_copy16(void* lds, const void* g) {
  __builtin_amdgcn_global_load_lds(
      (const __attribute__((address_space(1))) unsigned int*)g,
      (__attribute__((address_space(3))) unsigned int*)lds, 16, 0, 0);
}

// 8 fp32 -> bf16x8 via packed cvt (RNE, matches f2bf)
__device__ __forceinline__ bf16x8 cvt8(f32x4 lo, f32x4 hi) {
  union { bf16x8 v; uint32_t w[4]; } u;
  asm("v_cvt_pk_bf16_f32 %0, %1, %2" : "=v"(u.w[0]) : "v"(lo[0]), "v"(lo[1]));
  asm("v_cvt_pk_bf16_f32 %0, %1, %2" : "=v"(u.w[1]) : "v"(lo[2]), "v"(lo[3]));
  asm("v_cvt_pk_bf16_f32 %0, %1, %2" : "=v"(u.w[2]) : "v"(hi[0]), "v"(hi[1]));
  asm("v_cvt_pk_bf16_f32 %0, %1, %2" : "=v"(u.w[3]) : "v"(hi[2]), "v"(hi[3]));
  return u.v;
}

// ---------------- 4 weight transpose-converts ----------------
__global__ __launch_bounds__(256) void k_wtrans4(const float* __restrict__ w0,
                                                 const float* __restrict__ w1,
                                                 const float* __restrict__ w2,
                                                 const float* __restrict__ w3,
                                                 u16* __restrict__ dstbase) {
  const float* W = (blockIdx.z == 0) ? w0 : (blockIdx.z == 1) ? w1
                   : (blockIdx.z == 2) ? w2 : w3;
  u16* WT = dstbase + (size_t)blockIdx.z * 1048576;
  __shared__ float t[32][33];
  int bx = blockIdx.x, by = blockIdx.y;
  int tid = threadIdx.x;
  int c = tid & 31, r0 = tid >> 5;
#pragma unroll
  for (int i = 0; i < 4; ++i) {
    int r = r0 + i * 8;
    t[r][c] = W[(size_t)(by * 32 + r) * 1024 + bx * 32 + c];
  }
  __syncthreads();
#pragma unroll
  for (int i = 0; i < 4; ++i) {
    int r = r0 + i * 8;
    WT[(size_t)(bx * 32 + r) * 1024 + by * 32 + c] = f2bf(t[c][r]);
  }
}

// ---------------- batched V transpose: VP view (64,1024,64) -> VT (64,64,1024) ----------------
__global__ __launch_bounds__(256) void k_vtrans(const u16* __restrict__ VP, u16* __restrict__ VT) {
  int jt = blockIdx.x;
  int bh = blockIdx.y;
  __shared__ u16 t[64][65];
  int tid = threadIdx.x;
  const u16* src = VP + (size_t)bh * 65536 + (size_t)jt * 64 * 64;
#pragma unroll
  for (int i = 0; i < 16; ++i) {
    int e = tid + i * 256;
    t[e >> 6][e & 63] = src[e];
  }
  __syncthreads();
  u16* dst = VT + (size_t)bh * 65536 + jt * 64;
#pragma unroll
  for (int i = 0; i < 16; ++i) {
    int e = tid + i * 256;
    int d = e >> 6, j = e & 63;
    dst[(size_t)d * 1024 + j] = t[j][d];
  }
}

// ---------------- fused QKV GEMM (fp32-A direct) + attn upper-triangle zero-fill ----------------
// 1792 blocks: per XCD (id&7): 224 seq -> 32 groups of 7 (3 GEMM + 4 zero).
// GEMM: C(12288x1024 bf16) = [q;k;v](fp32) x wT[z]^T, XCD-chunked bm.
// Zero blocks: write fp32 zeros to fully-masked attn tiles (runs concurrent w/ GEMM compute).
__global__ __launch_bounds__(256) void k_gemm_qkv(const float* __restrict__ q,
                                                  const float* __restrict__ k,
                                                  const float* __restrict__ v,
                                                  const u16* __restrict__ wT,
                                                  u16* __restrict__ C,
                                                  float* __restrict__ attnp) {
  __shared__ __align__(16) float Asm[2][4096];  // 128x32 fp32 x2 (swizzled cols)
  __shared__ __align__(16) u16 Bsm[2][4096];    // 128x32 bf16 x2
  int id = blockIdx.x;
  int xcd = id & 7, seq = id >> 3;
  int grp = seq / 7, r7 = seq % 7;
  int tid = threadIdx.x;
  if (r7 >= 3) {
    // ---- zero-fill block ----
    int zid = xcd * 128 + grp * 4 + (r7 - 3);  // [0,1024)
    int bh = zid >> 4, qb = zid & 15;
    int W = 960 - 64 * qb;  // masked cols (full tiles) for this 64-row block
    if (W > 0 && tid * 4 < W) {
      float* base = attnp + (size_t)bh * 1048576 + (size_t)qb * 65536 + (qb + 1) * 64 + tid * 4;
      float4 z = {0.f, 0.f, 0.f, 0.f};
#pragma unroll 8
      for (int row = 0; row < 64; ++row) *(float4*)(base + row * 1024) = z;
    }
    return;
  }
  int gi = grp * 3 + r7;           // [0,96) within this xcd
  int bn = gi & 7;
  int bm = xcd * 12 + (gi >> 3);   // [0,96): same A-panel's 8 bn-blocks adjacent in time
  int z = bm >> 5;                 // 0=q,1=k,2=v
  int wave = tid >> 6, lane = tid & 63;
  int wr = wave >> 1, wc = wave & 1;
  int fl = lane & 15, fg = lane >> 4;
  f32x4 acc[4][4] = {};

  const char* Ab = (const char*)((z == 0 ? q : z == 1 ? k : v) + (size_t)(bm & 31) * 131072);
  const char* Bb = (const char*)(wT + (size_t)z * 1048576 + (size_t)bn * 131072);

#define ASTAGE(buf, kt)                                                        \
  {                                                                            \
    _Pragma("unroll") for (int is = 0; is < 4; ++is) {                         \
      int o = is * 4096 + wave * 1024 + lane * 16;                             \
      int row = o >> 7, cb = o & 127;                                          \
      async_copy16((char*)Asm[buf] + is * 4096 + wave * 1024,                  \
                   Ab + (size_t)row * 4096 + (kt) * 4 + (cb ^ ((row & 7) << 4))); \
    }                                                                          \
  }
#define BSTAGE(buf, kt)                                                        \
  {                                                                            \
    _Pragma("unroll") for (int is = 0; is < 2; ++is) {                         \
      int o = is * 4096 + wave * 1024 + lane * 16;                             \
      int row = o >> 6, cb = o & 63;                                           \
      async_copy16((char*)Bsm[buf] + is * 4096 + wave * 1024,                  \
                   Bb + (size_t)row * 2048 + (kt) * 2 + cb);                   \
    }                                                                          \
  }

  ASTAGE(0, 0);
  BSTAGE(0, 0);
  __syncthreads();
  int cur = 0;
  for (int kt = 0; kt < 1024; kt += 32) {
    if (kt + 32 < 1024) {
      ASTAGE(cur ^ 1, kt + 32);
      BSTAGE(cur ^ 1, kt + 32);
    }
    bf16x8 af[4], bfr[4];
#pragma unroll
    for (int m = 0; m < 4; ++m) {
      int R = wr * 64 + m * 16 + fl;
      const char* ar = (const char*)Asm[cur] + R * 128;
      int s = (R & 7) << 4;
      f32x4 lo = *(const f32x4*)(ar + ((fg * 32) ^ s));
      f32x4 hi = *(const f32x4*)(ar + ((fg * 32 + 16) ^ s));
      af[m] = cvt8(lo, hi);
    }
#pragma unroll
    for (int n = 0; n < 4; ++n)
      bfr[n] = *(const bf16x8*)((const char*)Bsm[cur] + (wc * 64 + n * 16 + fl) * 64 + fg * 16);
#pragma unroll
    for (int m = 0; m < 4; ++m)
#pragma unroll
      for (int n = 0; n < 4; ++n)
        acc[m][n] = MFMA_BF16(af[m], bfr[n], acc[m][n]);
    __syncthreads();
    cur ^= 1;
  }
#undef ASTAGE
#undef BSTAGE

  // epilogue: per-wave LDS stage (dead Asm), 16B bf16 stores
  float* EP = (float*)&Asm[0][0] + wave * 1088;  // 16x68
  int colbase = bn * 128 + wc * 64;
#pragma unroll
  for (int m = 0; m < 4; ++m) {
    int rowbase = bm * 128 + wr * 64 + m * 16;
#pragma unroll
    for (int n = 0; n < 4; ++n)
#pragma unroll
      for (int r = 0; r < 4; ++r)
        EP[(fg * 4 + r) * 68 + n * 16 + fl] = acc[m][n][r];
#pragma unroll
    for (int j = 0; j < 2; ++j) {
      int row = (lane >> 3) + 8 * j;
      int colf = (lane & 7) * 8;
      const float* sp = &EP[row * 68 + colf];
      us4 lo4, hi4;
#pragma unroll
      for (int i = 0; i < 4; ++i) { lo4[i] = f2bf(sp[i]); hi4[i] = f2bf(sp[4 + i]); }
      u16* d = C + (size_t)(rowbase + row) * 1024 + colbase + colf;
      *(us4*)d = lo4;
      *(us4*)(d + 4) = hi4;
    }
  }
}

// ---------------- barrier-free fused causal attention ----------------
// QP/KP: (64,1024,64) bf16 flat; VT: (64,64,1024) bf16
// Writes attn lower+diagonal tiles (upper tiles zeroed by k_gemm_qkv) + AO bf16.
// Zero __syncthreads: K read directly from global (L2-resident per XCD); Ps/Pt are per-wave.
__global__ __launch_bounds__(256) void k_attn(const u16* __restrict__ QP,
                                              const u16* __restrict__ KP,
                                              const u16* __restrict__ VT,
                                              float* __restrict__ attn,
                                              u16* __restrict__ AO) {
  int bh = blockIdx.x;       // head: XCD = bh%8 -> K/V L2-resident
  int qb = 15 - blockIdx.y;  // heavy q-blocks first
  int tid = threadIdx.x;
  int wave = tid >> 6, lane = tid & 63;
  int fl = lane & 15, fg = lane >> 4;
  int qw = qb * 64 + wave * 16;

  const u16* Qb = QP + (size_t)bh * 65536;
  const u16* Kb = KP + (size_t)bh * 65536;
  const u16* Vb = VT + (size_t)bh * 65536;
  float* Ab = attn + (size_t)bh * 1048576;

  __shared__ __align__(16) float Ps[4][16][36];  // per-wave fp32 P staging
  __shared__ __align__(16) u16 Pt[4][16][64];    // per-wave bf16 P for PV

  bf16x8 qf0 = *(const bf16x8*)(Qb + (size_t)(qw + fl) * 64 + fg * 8);
  bf16x8 qf1 = *(const bf16x8*)(Qb + (size_t)(qw + fl) * 64 + 32 + fg * 8);

  float den[4] = {0.f, 0.f, 0.f, 0.f};

  // ---- pass 1: row denominators (no LDS, no barriers) ----
  for (int jt = 0; jt <= qb; ++jt) {
    int j0 = jt * 64;
    f32x4 c[4] = {};
#pragma unroll
    for (int n = 0; n < 4; ++n) {
      const u16* kp = Kb + (size_t)(j0 + n * 16 + fl) * 64;
      bf16x8 k0 = *(const bf16x8*)(kp + fg * 8);
      bf16x8 k1 = *(const bf16x8*)(kp + 32 + fg * 8);
      c[n] = MFMA_BF16(qf0, k0, c[n]);
      c[n] = MFMA_BF16(qf1, k1, c[n]);
    }
#pragma unroll
    for (int r = 0; r < 4; ++r) {
      int row = qw + fg * 4 + r;
      float sum = 0.f;
#pragma unroll
      for (int n = 0; n < 4; ++n) {
        int col = j0 + n * 16 + fl;
        sum += (col > row) ? 0.f : __expf(c[n][r] * 0.03125f);
      }
#pragma unroll
      for (int o2 = 1; o2 < 16; o2 <<= 1) sum += __shfl_xor(sum, o2);
      den[r] += sum;
    }
  }

  float invden[4];
#pragma unroll
  for (int r = 0; r < 4; ++r) invden[r] = 1.0f / den[r];

  f32x4 oacc[4] = {};

  // ---- pass 2: probabilities (early coalesced store) + PV ----
  for (int jt = 0; jt <= qb; ++jt) {
    int j0 = jt * 64;
    f32x4 c[4] = {};
#pragma unroll
    for (int n = 0; n < 4; ++n) {
      const u16* kp = Kb + (size_t)(j0 + n * 16 + fl) * 64;
      bf16x8 k0 = *(const bf16x8*)(kp + fg * 8);
      bf16x8 k1 = *(const bf16x8*)(kp + 32 + fg * 8);
      c[n] = MFMA_BF16(qf0, k0, c[n]);
      c[n] = MFMA_BF16(qf1, k1, c[n]);
    }
    float pv_[4][4];
#pragma unroll
    for (int r = 0; r < 4; ++r) {
      int row = qw + fg * 4 + r;
#pragma unroll
      for (int n = 0; n < 4; ++n) {
        int col = j0 + n * 16 + fl;
        pv_[n][r] = (col > row) ? 0.f : __expf(c[n][r] * 0.03125f) * invden[r];
      }
    }
    // early coalesced fp32 stores (latency hidden under V loads + PV MFMAs)
#pragma unroll
    for (int t = 0; t < 2; ++t) {
#pragma unroll
      for (int n2 = 0; n2 < 2; ++n2)
#pragma unroll
        for (int r = 0; r < 4; ++r)
          Ps[wave][fg * 4 + r][n2 * 16 + fl] = pv_[t * 2 + n2][r];
#pragma unroll
      for (int i = 0; i < 2; ++i) {
        int idx = i * 64 + lane;
        int r16 = idx >> 3, f4 = idx & 7;
        float4 val = *(const float4*)(&Ps[wave][r16][f4 * 4]);
        *(float4*)(Ab + (size_t)(qw + r16) * 1024 + j0 + t * 32 + f4 * 4) = val;
      }
    }
#pragma unroll
    for (int r = 0; r < 4; ++r)
#pragma unroll
      for (int n = 0; n < 4; ++n)
        Pt[wave][fg * 4 + r][n * 16 + fl] = f2bf(pv_[n][r]);
    bf16x8 pa0 = *(const bf16x8*)(&Pt[wave][fl][fg * 8]);
    bf16x8 pa1 = *(const bf16x8*)(&Pt[wave][fl][32 + fg * 8]);
#pragma unroll
    for (int n = 0; n < 4; ++n) {
      const u16* vp = Vb + (size_t)(n * 16 + fl) * 1024 + j0;
      bf16x8 v0 = *(const bf16x8*)(vp + fg * 8);
      bf16x8 v1 = *(const bf16x8*)(vp + 32 + fg * 8);
      oacc[n] = MFMA_BF16(pa0, v0, oacc[n]);
      oacc[n] = MFMA_BF16(pa1, v1, oacc[n]);
    }
  }

  // ---- AO write via per-wave Pt staging, 16B stores ----
#pragma unroll
  for (int n = 0; n < 4; ++n)
#pragma unroll
    for (int r = 0; r < 4; ++r)
      Pt[wave][fg * 4 + r][n * 16 + fl] = f2bf(oacc[n][r]);
#pragma unroll
  for (int j = 0; j < 2; ++j) {
    int row = (lane >> 3) + 8 * j;
    int colf = (lane & 7) * 8;
    bf16x8 val = *(const bf16x8*)(&Pt[wave][row][colf]);
    *(bf16x8*)(AO + (size_t)bh * 65536 + (size_t)(qw + row) * 64 + colf) = val;
  }
}

// ---------------- output projection + residual (bf16 A) ----------------
__global__ __launch_bounds__(256) void k_gemm_out(const u16* __restrict__ A,
                                                  const u16* __restrict__ BT,
                                                  float* __restrict__ Cf,
                                                  const float* __restrict__ res) {
  __shared__ __align__(16) u16 SM[4][4096];
  int bm, bn;
  {
    int wg = blockIdx.x + blockIdx.y * 8;
    int xcd = wg & 7, idx = wg >> 3;
    bm = xcd * 4 + (idx & 3);
    bn = idx >> 2;
  }
  int tid = threadIdx.x;
  int wave = tid >> 6, lane = tid & 63;
  int wr = wave >> 1, wc = wave & 1;
  int fl = lane & 15, fg = lane >> 4;
  f32x4 acc[4][4] = {};

  const char* Abase = (const char*)(A + (size_t)bm * 131072);
  const char* Bbase = (const char*)(BT + (size_t)bn * 131072);
  int off = wave * 1024 + lane * 16;

#define GSTAGE(buf, kt)                                                        \
  {                                                                            \
    _Pragma("unroll") for (int is = 0; is < 2; ++is) {                         \
      int o = is * 4096 + off;                                                 \
      int row = o >> 6, cb = o & 63;                                           \
      async_copy16((char*)SM[buf] + is * 4096 + wave * 1024,                   \
                   Abase + (size_t)row * 2048 + (kt) * 2 + cb);                \
      async_copy16((char*)SM[2 + (buf)] + is * 4096 + wave * 1024,             \
                   Bbase + (size_t)row * 2048 + (kt) * 2 + cb);                \
    }                                                                          \
  }

  GSTAGE(0, 0);
  __syncthreads();
  int cur = 0;
  for (int kt = 0; kt < 1024; kt += 32) {
    if (kt + 32 < 1024) GSTAGE(cur ^ 1, kt + 32);
    bf16x8 af[4], bfr[4];
#pragma unroll
    for (int m = 0; m < 4; ++m)
      af[m] = *(const bf16x8*)((const char*)SM[cur] + (wr * 64 + m * 16 + fl) * 64 + fg * 16);
#pragma unroll
    for (int n = 0; n < 4; ++n)
      bfr[n] = *(const bf16x8*)((const char*)SM[2 + cur] + (wc * 64 + n * 16 + fl) * 64 + fg * 16);
#pragma unroll
    for (int m = 0; m < 4; ++m)
#pragma unroll
      for (int n = 0; n < 4; ++n)
        acc[m][n] = MFMA_BF16(af[m], bfr[n], acc[m][n]);
    __syncthreads();
    cur ^= 1;
  }
#undef GSTAGE

  float* EP = (float*)&SM[0][0] + wave * 1088;
  int colbase = bn * 128 + wc * 64;
#pragma unroll
  for (int m = 0; m < 4; ++m) {
    int rowbase = bm * 128 + wr * 64 + m * 16;
#pragma unroll
    for (int n = 0; n < 4; ++n)
#pragma unroll
      for (int r = 0; r < 4; ++r)
        EP[(fg * 4 + r) * 68 + n * 16 + fl] = acc[m][n][r];
#pragma unroll
    for (int j = 0; j < 4; ++j) {
      int row = (lane >> 4) + 4 * j;
      int colf = (lane & 15) * 4;
      float4 val = *(const float4*)(&EP[row * 68 + colf]);
      size_t gidx = (size_t)(rowbase + row) * 1024 + colbase + colf;
      float4 rr = *(const float4*)(res + gidx);
      val.x += rr.x; val.y += rr.y; val.z += rr.z; val.w += rr.w;
      *(float4*)(Cf + gidx) = val;
    }
  }
}

// ---------------- in-place LayerNorm over rows of 1024 ----------------
__global__ __launch_bounds__(256) void k_lnorm(float* __restrict__ io,
                                               const float* __restrict__ g,
                                               const float* __restrict__ b) {
  int row = blockIdx.x, tid = threadIdx.x;
  float* p = io + (size_t)row * 1024 + tid * 4;
  float4 x = *(const float4*)p;
  float s1 = x.x + x.y + x.z + x.w;
  float s2 = x.x * x.x + x.y * x.y + x.z * x.z + x.w * x.w;
#pragma unroll
  for (int o = 1; o < 64; o <<= 1) {
    s1 += __shfl_xor(s1, o);
    s2 += __shfl_xor(s2, o);
  }
  __shared__ float r1[4], r2[4];
  int wave = tid >> 6;
  if ((tid & 63) == 0) { r1[wave] = s1; r2[wave] = s2; }
  __syncthreads();
  s1 = r1[0] + r1[1] + r1[2] + r1[3];
  s2 = r2[0] + r2[1] + r2[2] + r2[3];
  float mu = s1 * (1.0f / 1024.0f);
  float var = s2 * (1.0f / 1024.0f) - mu * mu;
  float rs = rsqrtf(var + 1e-6f);
  float4 gg = *(const float4*)(g + tid * 4);
  float4 bb = *(const float4*)(b + tid * 4);
  float4 y;
  y.x = (x.x - mu) * rs * gg.x + bb.x;
  y.y = (x.y - mu) * rs * gg.y + bb.y;
  y.z = (x.z - mu) * rs * gg.z + bb.z;
  y.w = (x.w - mu) * rs * gg.w + bb.w;
  *(float4*)p = y;
}

extern "C" void kernel_launch(void* const* d_in, const int* in_sizes, int n_in,
                              void* d_out, int out_size, void* d_ws, size_t ws_size,
                              hipStream_t stream) {
  const float* q = (const float*)d_in[0];
  const float* k = (const float*)d_in[1];
  const float* v = (const float*)d_in[2];
  const float* w_q = (const float*)d_in[3];
  const float* w_k = (const float*)d_in[4];
  const float* w_v = (const float*)d_in[5];
  const float* w_o = (const float*)d_in[6];
  const float* ln_g = (const float*)d_in[7];
  const float* ln_b = (const float*)d_in[8];

  float* out = (float*)d_out;    // (4,1024,1024) fp32
  float* attnp = out + 4194304;  // (64,1024,1024) fp32

  char* ws = (char*)d_ws;
  u16* QP = (u16*)(ws);                // 8 MB  (QP,KP,VP contiguous: GEMM C rows 0..12287)
  u16* KP = QP + 4194304;              // +8 MB
  u16* VP = (u16*)(ws + (16u << 20));  // 8 MB
  u16* VT = (u16*)(ws + (24u << 20));  // 8 MB
  u16* AO = (u16*)(ws + (32u << 20));  // 8 MB
  u16* wT = (u16*)(ws + (40u << 20));  // 8 MB: wqT,wkT,wvT,woT
  u16* woT = wT + 3145728;

  k_wtrans4<<<dim3(32, 32, 4), 256, 0, stream>>>(w_q, w_k, w_v, w_o, wT);

  // fused QKV projections (fp32-A direct) + attn upper-triangle zero-fill
  k_gemm_qkv<<<1792, 256, 0, stream>>>(q, k, v, wT, QP, attnp);

  k_vtrans<<<dim3(16, 64), 256, 0, stream>>>(VP, VT);

  k_attn<<<dim3(64, 16), 256, 0, stream>>>(QP, KP, VT, attnp, AO);

  k_gemm_out<<<dim3(8, 32), 256, 0, stream>>>(AO, woT, out, q);

  k_lnorm<<<4096, 256, 0, stream>>>(out, ln_g, ln_b);
}

// Round 8
// 160.296 us; speedup vs baseline: 1.6013x; 1.6013x over previous
//
#include <hip/hip_runtime.h>
#include <stdint.h>

typedef unsigned short u16;
typedef __attribute__((ext_vector_type(8))) short bf16x8;
typedef __attribute__((ext_vector_type(4))) float f32x4;
typedef __attribute__((ext_vector_type(4))) unsigned short us4;

#define MFMA_BF16(a, b, c) __builtin_amdgcn_mfma_f32_16x16x32_bf16((a), (b), (c), 0, 0, 0)

__device__ __forceinline__ u16 f2bf(float f) {
  uint32_t u = __builtin_bit_cast(uint32_t, f);
  u += 0x7fffu + ((u >> 16) & 1u);
  return (u16)(u >> 16);
}

__device__ __forceinline__ void async_copy16(void* lds, const void* g) {
  __builtin_amdgcn_global_load_lds(
      (const __attribute__((address_space(1))) unsigned int*)g,
      (__attribute__((address_space(3))) unsigned int*)lds, 16, 0, 0);
}

// ---------------- merged: fp32->bf16 casts (q,k,v) + 4 weight transpose-converts ----------------
__global__ __launch_bounds__(256) void k_pre(const float* __restrict__ q,
                                             const float* __restrict__ k,
                                             const float* __restrict__ v,
                                             const float* __restrict__ w0,
                                             const float* __restrict__ w1,
                                             const float* __restrict__ w2,
                                             const float* __restrict__ w3,
                                             us4* __restrict__ qkvb,
                                             u16* __restrict__ wT) {
  __shared__ float t[32][33];
  int bid = blockIdx.x;
  int tid = threadIdx.x;
  if (bid < 12288) {
    int z = bid >> 12;
    const float4* src = (z == 0) ? (const float4*)q : (z == 1) ? (const float4*)k : (const float4*)v;
    int i = (bid & 4095) * 256 + tid;
    float4 val = src[i];
    us4 o;
    o[0] = f2bf(val.x); o[1] = f2bf(val.y); o[2] = f2bf(val.z); o[3] = f2bf(val.w);
    qkvb[(size_t)z * 1048576 + i] = o;
  } else {
    int w = bid - 12288;
    int z = w >> 10, r_ = w & 1023;
    int bx = r_ & 31, by = r_ >> 5;
    const float* W = (z == 0) ? w0 : (z == 1) ? w1 : (z == 2) ? w2 : w3;
    u16* WT = wT + (size_t)z * 1048576;
    int c = tid & 31, r0 = tid >> 5;
#pragma unroll
    for (int i = 0; i < 4; ++i) {
      int r = r0 + i * 8;
      t[r][c] = W[(size_t)(by * 32 + r) * 1024 + bx * 32 + c];
    }
    __syncthreads();
#pragma unroll
    for (int i = 0; i < 4; ++i) {
      int r = r0 + i * 8;
      WT[(size_t)(bx * 32 + r) * 1024 + by * 32 + c] = f2bf(t[c][r]);
    }
  }
}

// ---------------- batched V transpose: VP view (64,1024,64) -> VT (64,64,1024) ----------------
// NOTE: VP is the linear (flat .view) reinterpretation of the projection buffer — do not
// "fuse" this into the GEMM epilogue with (b,l,h*d) semantics (round-6 bug).
__global__ __launch_bounds__(256) void k_vtrans(const u16* __restrict__ VP, u16* __restrict__ VT) {
  int jt = blockIdx.x;
  int bh = blockIdx.y;
  __shared__ u16 t[64][65];
  int tid = threadIdx.x;
  const u16* src = VP + (size_t)bh * 65536 + (size_t)jt * 64 * 64;
#pragma unroll
  for (int i = 0; i < 16; ++i) {
    int e = tid + i * 256;
    t[e >> 6][e & 63] = src[e];
  }
  __syncthreads();
  u16* dst = VT + (size_t)bh * 65536 + jt * 64;
#pragma unroll
  for (int i = 0; i < 16; ++i) {
    int e = tid + i * 256;
    int d = e >> 6, j = e & 63;
    dst[(size_t)d * 1024 + j] = t[j][d];
  }
}

// ---------------- bf16 GEMM: C(MxN) = A(MxK) * BT(NxK)^T (128x128 tile) ----------------
// 2-phase double-buffered staging + XCD-chunked swizzle + LDS-staged vector epilogue.
// mode 0: C -> bf16 Cb.   mode 1: C + res -> fp32 Cf.
// wgrp 1: B matrix selected per 32-block group of bm (fused QKV).
__global__ __launch_bounds__(256) void k_gemm_bt(const u16* __restrict__ A,
                                                 const u16* __restrict__ BT,
                                                 u16* __restrict__ Cb, float* __restrict__ Cf,
                                                 const float* __restrict__ res,
                                                 int N, int K, int mode, int wgrp) {
  __shared__ __align__(16) u16 SM[4][4096];  // [0..1]=A dbuf, [2..3]=B dbuf; reused by epilogue
  int bm, bn;
  {
    int wg = blockIdx.x + blockIdx.y * gridDim.x;  // gridDim.x == 8
    int per = gridDim.y >> 3;
    int xcd = wg & 7;
    int idx = wg >> 3;
    bm = xcd * per + (idx % per);
    bn = idx / per;
  }
  int tid = threadIdx.x;
  int wave = tid >> 6, lane = tid & 63;
  int wr = wave >> 1, wc = wave & 1;
  int fl = lane & 15, fg = lane >> 4;
  f32x4 acc[4][4] = {};

  const char* Abase = (const char*)(A + (size_t)bm * 128 * K);
  const char* Bbase = (const char*)(BT + (wgrp ? (size_t)(bm >> 5) * 1048576 : 0) +
                                    (size_t)bn * 128 * K);
  int off = wave * 1024 + lane * 16;

#define GSTAGE(buf, kt)                                                              \
  {                                                                                  \
    _Pragma("unroll") for (int is = 0; is < 2; ++is) {                               \
      int o = is * 4096 + off;                                                       \
      int row = o >> 6, cb = o & 63;                                                 \
      async_copy16((char*)SM[buf] + is * 4096 + wave * 1024,                         \
                   Abase + (size_t)row * (K * 2) + (kt) * 2 + cb);                   \
      async_copy16((char*)SM[2 + (buf)] + is * 4096 + wave * 1024,                   \
                   Bbase + (size_t)row * (K * 2) + (kt) * 2 + cb);                   \
    }                                                                                \
  }

  GSTAGE(0, 0);
  __syncthreads();
  int cur = 0;
  for (int kt = 0; kt < K; kt += 32) {
    if (kt + 32 < K) GSTAGE(cur ^ 1, kt + 32);
    bf16x8 af[4], bfr[4];
#pragma unroll
    for (int m = 0; m < 4; ++m)
      af[m] = *(const bf16x8*)((const char*)SM[cur] + (wr * 64 + m * 16 + fl) * 64 + fg * 16);
#pragma unroll
    for (int n = 0; n < 4; ++n)
      bfr[n] = *(const bf16x8*)((const char*)SM[2 + cur] + (wc * 64 + n * 16 + fl) * 64 + fg * 16);
#pragma unroll
    for (int m = 0; m < 4; ++m)
#pragma unroll
      for (int n = 0; n < 4; ++n)
        acc[m][n] = MFMA_BF16(af[m], bfr[n], acc[m][n]);
    __syncthreads();
    cur ^= 1;
  }
#undef GSTAGE

  // ---- epilogue: stage per-wave 16x64 fp32 tile in (dead) SM, vector stores ----
  float* EP = (float*)&SM[0][0] + wave * 2048;  // 8 KB per wave
  int colbase = bn * 128 + wc * 64;
#pragma unroll
  for (int m = 0; m < 4; ++m) {
    int rowbase = bm * 128 + wr * 64 + m * 16;
#pragma unroll
    for (int n = 0; n < 4; ++n)
#pragma unroll
      for (int r = 0; r < 4; ++r)
        EP[(fg * 4 + r) * 68 + n * 16 + fl] = acc[m][n][r];
    if (mode) {
#pragma unroll
      for (int j = 0; j < 4; ++j) {
        int row = (lane >> 4) + 4 * j;
        int colf = (lane & 15) * 4;
        float4 val = *(const float4*)(&EP[row * 68 + colf]);
        size_t gidx = (size_t)(rowbase + row) * N + colbase + colf;
        float4 rr = *(const float4*)(res + gidx);
        val.x += rr.x; val.y += rr.y; val.z += rr.z; val.w += rr.w;
        *(float4*)(Cf + gidx) = val;
      }
    } else {
#pragma unroll
      for (int j = 0; j < 2; ++j) {
        int row = (lane >> 3) + 8 * j;
        int colf = (lane & 7) * 8;
        const float* s = &EP[row * 68 + colf];
        us4 lo, hi;
#pragma unroll
        for (int i = 0; i < 4; ++i) { lo[i] = f2bf(s[i]); hi[i] = f2bf(s[4 + i]); }
        u16* d = Cb + (size_t)(rowbase + row) * N + colbase + colf;
        *(us4*)d = lo;
        *(us4*)(d + 4) = hi;
      }
    }
  }
}

// ---------------- output projection + residual: 64x128 tile, 512 blocks (2/CU) ----------------
// LDS map (bytes): A dbuf 2x4096 at [0,8192); B dbuf 2x8192 at [8192,24576).
// A tile = 64 rows x 32 k x 2B = 4096 B; B tile = 128 rows x 32 k x 2B = 8192 B.
__global__ __launch_bounds__(256) void k_gemm_out64(const u16* __restrict__ A,
                                                    const u16* __restrict__ BT,
                                                    float* __restrict__ Cf,
                                                    const float* __restrict__ res) {
  __shared__ __align__(16) u16 SM[12288];  // 24576 B
  char* base = (char*)SM;
  int bm, bn;
  {
    int wg = blockIdx.x + blockIdx.y * 8;  // grid (8,64)
    int xcd = wg & 7, idx = wg >> 3;
    bm = xcd * 8 + (idx & 7);   // 0..63 (64-row tiles)
    bn = idx >> 3;              // 0..7
  }
  int tid = threadIdx.x;
  int wave = tid >> 6, lane = tid & 63;
  int wr = wave >> 1, wc = wave & 1;
  int fl = lane & 15, fg = lane >> 4;
  f32x4 acc[2][4] = {};

  const char* Abase = (const char*)(A + (size_t)bm * 65536);    // 64 rows x 1024 k
  const char* Bbase = (const char*)(BT + (size_t)bn * 131072);  // 128 rows x 1024 k

#define OSTAGE(buf, kt)                                                          \
  {                                                                              \
    int oA = wave * 1024 + lane * 16;                                            \
    int rowA = oA >> 6, cbA = oA & 63;                                           \
    async_copy16(base + (buf) * 4096 + wave * 1024,                              \
                 Abase + (size_t)rowA * 2048 + (kt) * 2 + cbA);                  \
    _Pragma("unroll") for (int is = 0; is < 2; ++is) {                           \
      int oB = is * 4096 + wave * 1024 + lane * 16;                              \
      int rowB = oB >> 6, cbB = oB & 63;                                         \
      async_copy16(base + 8192 + (buf) * 8192 + is * 4096 + wave * 1024,         \
                   Bbase + (size_t)rowB * 2048 + (kt) * 2 + cbB);                \
    }                                                                            \
  }

  OSTAGE(0, 0);
  __syncthreads();
  int cur = 0;
  for (int kt = 0; kt < 1024; kt += 32) {
    if (kt + 32 < 1024) OSTAGE(cur ^ 1, kt + 32);
    const char* Ab = base + cur * 4096;
    const char* Bb = base + 8192 + cur * 8192;
    bf16x8 af[2], bfr[4];
#pragma unroll
    for (int m = 0; m < 2; ++m)
      af[m] = *(const bf16x8*)(Ab + (wr * 32 + m * 16 + fl) * 64 + fg * 16);
#pragma unroll
    for (int n = 0; n < 4; ++n)
      bfr[n] = *(const bf16x8*)(Bb + (wc * 64 + n * 16 + fl) * 64 + fg * 16);
#pragma unroll
    for (int m = 0; m < 2; ++m)
#pragma unroll
      for (int n = 0; n < 4; ++n)
        acc[m][n] = MFMA_BF16(af[m], bfr[n], acc[m][n]);
    __syncthreads();
    cur ^= 1;
  }
#undef OSTAGE

  // ---- epilogue: per-wave 16x68 fp32 stage in dead LDS (4 x 4352 B <= 24576 B) ----
  float* EP = (float*)base + wave * 1088;
  int colbase = bn * 128 + wc * 64;
#pragma unroll
  for (int m = 0; m < 2; ++m) {
    int rowbase = bm * 64 + wr * 32 + m * 16;
#pragma unroll
    for (int n = 0; n < 4; ++n)
#pragma unroll
      for (int r = 0; r < 4; ++r)
        EP[(fg * 4 + r) * 68 + n * 16 + fl] = acc[m][n][r];
#pragma unroll
    for (int j = 0; j < 4; ++j) {
      int row = (lane >> 4) + 4 * j;
      int colf = (lane & 15) * 4;
      float4 val = *(const float4*)(&EP[row * 68 + colf]);
      size_t gidx = (size_t)(rowbase + row) * 1024 + colbase + colf;
      float4 rr = *(const float4*)(res + gidx);
      val.x += rr.x; val.y += rr.y; val.z += rr.z; val.w += rr.w;
      *(float4*)(Cf + gidx) = val;
    }
  }
}

// ---------------- fused causal attention (no-max softmax; scores are O(0.5)) ----------------
// QP/KP: (64 bh, 1024, 64) bf16; VT: (64 bh, 64 d, 1024 j) bf16
// attn: (64, 1024, 1024) fp32 out; AO: (64 bh, 1024, 64) bf16 out
__global__ __launch_bounds__(256) void k_attn(const u16* __restrict__ QP,
                                              const u16* __restrict__ KP,
                                              const u16* __restrict__ VT,
                                              float* __restrict__ attn,
                                              u16* __restrict__ AO) {
  int bh = blockIdx.x;   // head on fixed XCD (bh%8)
  int qb = 15 - blockIdx.y;
  int tid = threadIdx.x;
  int wave = tid >> 6, lane = tid & 63;
  int fl = lane & 15, fg = lane >> 4;
  int qw = qb * 64 + wave * 16;

  const u16* Qb = QP + (size_t)bh * 65536;
  const char* Kbyte = (const char*)(KP + (size_t)bh * 65536);
  const u16* Vb = VT + (size_t)bh * 65536;
  float* Ab = attn + (size_t)bh * 1048576;

  __shared__ __align__(16) u16 Ks[2][4096];      // 64x64 bf16 x2, XOR-swizzled rows
  __shared__ __align__(16) float Ps[4][16][36];  // fp32 P staging (two 32-col rounds)
  __shared__ __align__(16) u16 Pt[4][16][64];    // bf16 P for PV; reused for AO staging

#define KSTAGE(buf, jt)                                                                 \
  {                                                                                     \
    _Pragma("unroll") for (int c2 = 0; c2 < 2; ++c2) {                                  \
      int o = c2 * 4096 + wave * 1024 + lane * 16;                                      \
      int row = o >> 7, col = o & 127;                                                  \
      async_copy16((char*)Ks[buf] + c2 * 4096 + wave * 1024,                            \
                   Kbyte + (size_t)((jt) * 64 + row) * 128 + (col ^ ((row & 7) << 4))); \
    }                                                                                   \
  }

  bf16x8 qf0 = *(const bf16x8*)(Qb + (size_t)(qw + fl) * 64 + fg * 8);
  bf16x8 qf1 = *(const bf16x8*)(Qb + (size_t)(qw + fl) * 64 + 32 + fg * 8);

  float den[4] = {0.f, 0.f, 0.f, 0.f};

  // ---- pass 1: row denominators ----
  KSTAGE(0, 0);
  __syncthreads();
  int cur = 0;
  for (int jt = 0; jt <= qb; ++jt) {
    if (jt < qb) KSTAGE(cur ^ 1, jt + 1);
    int j0 = jt * 64;
    f32x4 c[4] = {};
#pragma unroll
    for (int n = 0; n < 4; ++n) {
      int r = n * 16 + fl;
      bf16x8 k0 = *(const bf16x8*)((const char*)Ks[cur] + r * 128 + ((fg * 16) ^ ((r & 7) << 4)));
      bf16x8 k1 = *(const bf16x8*)((const char*)Ks[cur] + r * 128 + ((64 + fg * 16) ^ ((r & 7) << 4)));
      c[n] = MFMA_BF16(qf0, k0, c[n]);
      c[n] = MFMA_BF16(qf1, k1, c[n]);
    }
#pragma unroll
    for (int r = 0; r < 4; ++r) {
      int row = qw + fg * 4 + r;
      float sum = 0.f;
#pragma unroll
      for (int n = 0; n < 4; ++n) {
        int col = j0 + n * 16 + fl;
        sum += (col > row) ? 0.f : __expf(c[n][r] * 0.03125f);
      }
#pragma unroll
      for (int o2 = 1; o2 < 16; o2 <<= 1) sum += __shfl_xor(sum, o2);
      den[r] += sum;
    }
    __syncthreads();
    cur ^= 1;
  }

  float invden[4];
#pragma unroll
  for (int r = 0; r < 4; ++r) invden[r] = 1.0f / den[r];

  f32x4 oacc[4] = {};

  // ---- pass 2: probabilities (early coalesced store) + PV ----
  KSTAGE(0, 0);
  __syncthreads();
  cur = 0;
  for (int jt = 0; jt <= qb; ++jt) {
    if (jt < qb) KSTAGE(cur ^ 1, jt + 1);
    int j0 = jt * 64;
    f32x4 c[4] = {};
#pragma unroll
    for (int n = 0; n < 4; ++n) {
      int r = n * 16 + fl;
      bf16x8 k0 = *(const bf16x8*)((const char*)Ks[cur] + r * 128 + ((fg * 16) ^ ((r & 7) << 4)));
      bf16x8 k1 = *(const bf16x8*)((const char*)Ks[cur] + r * 128 + ((64 + fg * 16) ^ ((r & 7) << 4)));
      c[n] = MFMA_BF16(qf0, k0, c[n]);
      c[n] = MFMA_BF16(qf1, k1, c[n]);
    }
    // HOISTED V loads (independent of P): latency hides under exp + stores below
    bf16x8 vf0[4], vf1[4];
#pragma unroll
    for (int n = 0; n < 4; ++n) {
      const u16* vp = Vb + (size_t)(n * 16 + fl) * 1024 + j0;
      vf0[n] = *(const bf16x8*)(vp + fg * 8);
      vf1[n] = *(const bf16x8*)(vp + 32 + fg * 8);
    }
    // compute all probabilities into registers
    float pv_[4][4];  // [n][r]
#pragma unroll
    for (int r = 0; r < 4; ++r) {
      int row = qw + fg * 4 + r;
#pragma unroll
      for (int n = 0; n < 4; ++n) {
        int col = j0 + n * 16 + fl;
        pv_[n][r] = (col > row) ? 0.f : __expf(c[n][r] * 0.03125f) * invden[r];
      }
    }
    // EARLY coalesced fp32 attn stores (two 32-col rounds via per-wave LDS stage)
#pragma unroll
    for (int t = 0; t < 2; ++t) {
#pragma unroll
      for (int n2 = 0; n2 < 2; ++n2)
#pragma unroll
        for (int r = 0; r < 4; ++r)
          Ps[wave][fg * 4 + r][n2 * 16 + fl] = pv_[t * 2 + n2][r];
#pragma unroll
      for (int i = 0; i < 2; ++i) {
        int idx = i * 64 + lane;
        int r16 = idx >> 3, f4 = idx & 7;
        float4 val = *(const float4*)(&Ps[wave][r16][f4 * 4]);
        *(float4*)(Ab + (size_t)(qw + r16) * 1024 + j0 + t * 32 + f4 * 4) = val;
      }
    }
    // bf16 P for PV
#pragma unroll
    for (int r = 0; r < 4; ++r)
#pragma unroll
      for (int n = 0; n < 4; ++n)
        Pt[wave][fg * 4 + r][n * 16 + fl] = f2bf(pv_[n][r]);
    bf16x8 pa0 = *(const bf16x8*)(&Pt[wave][fl][fg * 8]);
    bf16x8 pa1 = *(const bf16x8*)(&Pt[wave][fl][32 + fg * 8]);
#pragma unroll
    for (int n = 0; n < 4; ++n) {
      oacc[n] = MFMA_BF16(pa0, vf0[n], oacc[n]);
      oacc[n] = MFMA_BF16(pa1, vf1[n], oacc[n]);
    }
    __syncthreads();
    cur ^= 1;
  }
#undef KSTAGE

  // ---- zero-fill masked tiles (coalesced) ----
  float4 z; z.x = 0.f; z.y = 0.f; z.z = 0.f; z.w = 0.f;
  for (int jt = qb + 1; jt < 16; ++jt) {
    int j0 = jt * 64;
#pragma unroll
    for (int i = 0; i < 4; ++i) {
      int idx = i * 64 + lane;
      int r16 = idx >> 4, f4 = idx & 15;
      *(float4*)(Ab + (size_t)(qw + r16) * 1024 + j0 + f4 * 4) = z;
    }
  }

  // ---- AO write: stage bf16 in (dead) Pt, 16B vector stores ----
#pragma unroll
  for (int n = 0; n < 4; ++n)
#pragma unroll
    for (int r = 0; r < 4; ++r)
      Pt[wave][fg * 4 + r][n * 16 + fl] = f2bf(oacc[n][r]);
#pragma unroll
  for (int j = 0; j < 2; ++j) {
    int row = (lane >> 3) + 8 * j;
    int colf = (lane & 7) * 8;
    bf16x8 val = *(const bf16x8*)(&Pt[wave][row][colf]);
    *(bf16x8*)(AO + (size_t)bh * 65536 + (size_t)(qw + row) * 64 + colf) = val;
  }
}

// ---------------- in-place LayerNorm over rows of 1024 ----------------
__global__ __launch_bounds__(256) void k_lnorm(float* __restrict__ io,
                                               const float* __restrict__ g,
                                               const float* __restrict__ b) {
  int row = blockIdx.x, tid = threadIdx.x;
  float* p = io + (size_t)row * 1024 + tid * 4;
  float4 x = *(const float4*)p;
  float s1 = x.x + x.y + x.z + x.w;
  float s2 = x.x * x.x + x.y * x.y + x.z * x.z + x.w * x.w;
#pragma unroll
  for (int o = 1; o < 64; o <<= 1) {
    s1 += __shfl_xor(s1, o);
    s2 += __shfl_xor(s2, o);
  }
  __shared__ float r1[4], r2[4];
  int wave = tid >> 6;
  if ((tid & 63) == 0) { r1[wave] = s1; r2[wave] = s2; }
  __syncthreads();
  s1 = r1[0] + r1[1] + r1[2] + r1[3];
  s2 = r2[0] + r2[1] + r2[2] + r2[3];
  float mu = s1 * (1.0f / 1024.0f);
  float var = s2 * (1.0f / 1024.0f) - mu * mu;
  float rs = rsqrtf(var + 1e-6f);
  float4 gg = *(const float4*)(g + tid * 4);
  float4 bb = *(const float4*)(b + tid * 4);
  float4 y;
  y.x = (x.x - mu) * rs * gg.x + bb.x;
  y.y = (x.y - mu) * rs * gg.y + bb.y;
  y.z = (x.z - mu) * rs * gg.z + bb.z;
  y.w = (x.w - mu) * rs * gg.w + bb.w;
  *(float4*)p = y;
}

extern "C" void kernel_launch(void* const* d_in, const int* in_sizes, int n_in,
                              void* d_out, int out_size, void* d_ws, size_t ws_size,
                              hipStream_t stream) {
  const float* q = (const float*)d_in[0];
  const float* k = (const float*)d_in[1];
  const float* v = (const float*)d_in[2];
  const float* w_q = (const float*)d_in[3];
  const float* w_k = (const float*)d_in[4];
  const float* w_v = (const float*)d_in[5];
  const float* w_o = (const float*)d_in[6];
  const float* ln_g = (const float*)d_in[7];
  const float* ln_b = (const float*)d_in[8];

  float* out = (float*)d_out;    // (4,1024,1024) fp32
  float* attnp = out + 4194304;  // (64,1024,1024) fp32

  char* ws = (char*)d_ws;
  u16* QP = (u16*)(ws);                 // 8 MB  } QP,KP,VP contiguous (GEMM C rows 0..12287)
  u16* VP = (u16*)(ws + (16u << 20));   // 8 MB
  u16* VT = (u16*)(ws + (24u << 20));   // 8 MB
  u16* AO = (u16*)(ws + (32u << 20));   // 8 MB
  u16* wT = (u16*)(ws + (40u << 20));   // 8 MB: wqT,wkT,wvT,woT
  u16* KP = QP + 4194304;
  u16* woT = wT + 3145728;

  // bf16 activations staged in the (not-yet-written) attn region of d_out
  u16* qkvb = (u16*)attnp;  // 24 MB: qb,kb,vb contiguous

  k_pre<<<16384, 256, 0, stream>>>(q, k, v, w_q, w_k, w_v, w_o, (us4*)qkvb, wT);

  // fused QKV projections: M = 3*4096 rows, B selected per 32-row-block group
  k_gemm_bt<<<dim3(8, 96), 256, 0, stream>>>(qkvb, wT, QP, nullptr, nullptr, 1024, 1024, 0, 1);

  k_vtrans<<<dim3(16, 64), 256, 0, stream>>>(VP, VT);

  k_attn<<<dim3(64, 16), 256, 0, stream>>>(QP, KP, VT, attnp, AO);

  k_gemm_out64<<<dim3(8, 64), 256, 0, stream>>>(AO, woT, out, q);

  k_lnorm<<<4096, 256, 0, stream>>>(out, ln_g, ln_b);
}